// Round 1
// baseline (1069.898 us; speedup 1.0000x reference)
//
#include <hip/hip_runtime.h>

#define NUM_NODES 10000
#define NUM_EDGES 320000
#define FEAT_DIM  256

// One thread per (edge, float4-of-features): 320000 * 64 threads.
// Coalesced float4 reads of msg; 4 fp32 atomicAdds into the target row.
__global__ __launch_bounds__(256) void scatter_add_kernel(
    const float4* __restrict__ msg4,   // [NUM_EDGES * 64]
    const int*    __restrict__ tgt,    // [NUM_EDGES] (second row of edge_index)
    float*        __restrict__ out)    // [NUM_NODES * FEAT_DIM]
{
    int idx = blockIdx.x * blockDim.x + threadIdx.x;   // 0 .. NUM_EDGES*64-1
    int e  = idx >> 6;     // edge id
    int f4 = idx & 63;     // which float4 within the 256-float row
    if (e >= NUM_EDGES) return;

    float4 v = msg4[(size_t)e * 64 + f4];
    int t = tgt[e];
    float* o = out + (size_t)t * FEAT_DIM + f4 * 4;
    atomicAdd(o + 0, v.x);
    atomicAdd(o + 1, v.y);
    atomicAdd(o + 2, v.z);
    atomicAdd(o + 3, v.w);
}

extern "C" void kernel_launch(void* const* d_in, const int* in_sizes, int n_in,
                              void* d_out, int out_size, void* d_ws, size_t ws_size,
                              hipStream_t stream) {
    const float4* msg4 = (const float4*)d_in[0];
    const int*    eidx = (const int*)d_in[1];          // [2, NUM_EDGES] row-major
    const int*    tgt  = eidx + NUM_EDGES;             // edge_index[1]
    float*        out  = (float*)d_out;

    // Harness poisons d_out with 0xAA before timing and never re-poisons:
    // we must zero it ourselves on every call. hipMemsetAsync is capture-safe.
    hipMemsetAsync(out, 0, (size_t)out_size * sizeof(float), stream);

    const int total  = NUM_EDGES * 64;                 // threads
    const int block  = 256;
    const int grid   = (total + block - 1) / block;    // 80000 blocks
    scatter_add_kernel<<<grid, block, 0, stream>>>(msg4, tgt, out);
}

// Round 2
// 100.724 us; speedup vs baseline: 10.6221x; 10.6221x over previous
//
#include <hip/hip_runtime.h>

#define NUM_NODES 10000
#define NUM_EDGES 320000
#define FEAT_DIM  256
#define MAXDEG    64   // Poisson(mean 32); overflow handled by fallback atomics

// ws layout: cursor[NUM_NODES] ints, then buckets[NUM_NODES*MAXDEG] ints (~2.6 MB)

// Phase 1: bucket edge ids per target node. Only 320k int atomics (vs 82M fp32).
__global__ __launch_bounds__(256) void fill_buckets(
    const float* __restrict__ msg,
    const int*   __restrict__ tgt,
    int*         __restrict__ cursor,
    int*         __restrict__ buckets,
    float*       __restrict__ out)
{
    int e = blockIdx.x * blockDim.x + threadIdx.x;
    if (e >= NUM_EDGES) return;
    int t = tgt[e];
    int idx = atomicAdd(&cursor[t], 1);
    if (idx < MAXDEG) {
        buckets[t * MAXDEG + idx] = e;
    } else {
        // Rare overflow (deg > 64): direct atomic scatter of this edge's row.
        const float* m = msg + (size_t)e * FEAT_DIM;
        float* o = out + (size_t)t * FEAT_DIM;
        for (int f = 0; f < FEAT_DIM; ++f) atomicAdd(o + f, m[f]);
    }
}

// Phase 2: one 64-lane group per node; lane owns one float4 of the 256-float row.
// Each msg row is read exactly once, coalesced (64 lanes x 16B = 1KB burst).
__global__ __launch_bounds__(256) void gather_sum(
    const float4* __restrict__ msg4,
    const int*    __restrict__ cursor,
    const int*    __restrict__ buckets,
    float4*       __restrict__ out4)
{
    int g    = threadIdx.x >> 6;            // 4 node-groups per block
    int lane = threadIdx.x & 63;
    int n    = blockIdx.x * 4 + g;
    if (n >= NUM_NODES) return;

    int deg = cursor[n];
    if (deg > MAXDEG) deg = MAXDEG;
    const int* bl = buckets + n * MAXDEG;

    float4 acc = make_float4(0.f, 0.f, 0.f, 0.f);
    int i = 0;
    for (; i + 2 <= deg; i += 2) {          // 2-deep unroll for load ILP
        int e0 = bl[i], e1 = bl[i + 1];
        float4 v0 = msg4[(size_t)e0 * 64 + lane];
        float4 v1 = msg4[(size_t)e1 * 64 + lane];
        acc.x += v0.x + v1.x;
        acc.y += v0.y + v1.y;
        acc.z += v0.z + v1.z;
        acc.w += v0.w + v1.w;
    }
    if (i < deg) {
        float4 v = msg4[(size_t)bl[i] * 64 + lane];
        acc.x += v.x; acc.y += v.y; acc.z += v.z; acc.w += v.w;
    }

    size_t o = (size_t)n * 64 + lane;
    float4 prev = out4[o];                   // holds rare fallback contributions (else 0)
    acc.x += prev.x; acc.y += prev.y; acc.z += prev.z; acc.w += prev.w;
    out4[o] = acc;
}

// Correct-but-slow fallback if ws is unexpectedly small (round-0 kernel).
__global__ __launch_bounds__(256) void scatter_add_kernel(
    const float4* __restrict__ msg4,
    const int*    __restrict__ tgt,
    float*        __restrict__ out)
{
    int idx = blockIdx.x * blockDim.x + threadIdx.x;
    int e  = idx >> 6;
    int f4 = idx & 63;
    if (e >= NUM_EDGES) return;
    float4 v = msg4[(size_t)e * 64 + f4];
    int t = tgt[e];
    float* o = out + (size_t)t * FEAT_DIM + f4 * 4;
    atomicAdd(o + 0, v.x);
    atomicAdd(o + 1, v.y);
    atomicAdd(o + 2, v.z);
    atomicAdd(o + 3, v.w);
}

extern "C" void kernel_launch(void* const* d_in, const int* in_sizes, int n_in,
                              void* d_out, int out_size, void* d_ws, size_t ws_size,
                              hipStream_t stream) {
    const float*  msg  = (const float*)d_in[0];
    const float4* msg4 = (const float4*)d_in[0];
    const int*    eidx = (const int*)d_in[1];   // [2, NUM_EDGES] row-major
    const int*    tgt  = eidx + NUM_EDGES;      // edge_index[1]
    float*        out  = (float*)d_out;

    const size_t need = (size_t)NUM_NODES * sizeof(int)
                      + (size_t)NUM_NODES * MAXDEG * sizeof(int);

    // Output must be zeroed every call (harness poisons 0xAA before timing).
    hipMemsetAsync(out, 0, (size_t)out_size * sizeof(float), stream);

    if (ws_size >= need) {
        int* cursor  = (int*)d_ws;
        int* buckets = cursor + NUM_NODES;
        hipMemsetAsync(cursor, 0, (size_t)NUM_NODES * sizeof(int), stream);

        fill_buckets<<<(NUM_EDGES + 255) / 256, 256, 0, stream>>>(
            msg, tgt, cursor, buckets, out);
        gather_sum<<<NUM_NODES / 4, 256, 0, stream>>>(
            msg4, cursor, buckets, (float4*)out);
    } else {
        const int total = NUM_EDGES * 64;
        scatter_add_kernel<<<(total + 255) / 256, 256, 0, stream>>>(msg4, tgt, out);
    }
}

// Round 3
// 96.001 us; speedup vs baseline: 11.1446x; 1.0492x over previous
//
#include <hip/hip_runtime.h>

#define NUM_NODES 10000
#define NUM_EDGES 320000
#define FEAT_DIM  256
#define OVF_CAP   4096   // overflow edge slots (paranoia; expected 0 used)

// ws layout:
//   int cursor[NUM_NODES]       -- per-node degree counters
//   int ovf_cnt                 -- overflow counter
//   int ovf[2*OVF_CAP]          -- (edge, node) overflow pairs
//   int buckets[NUM_NODES*cap]  -- per-node edge-id lists (cap chosen at runtime)

// Phase 1: bucket edge ids per target node (320k int atomics on L2-resident cursor).
__global__ __launch_bounds__(256) void fill_buckets(
    const int* __restrict__ tgt,
    int*       __restrict__ cursor,
    int*       __restrict__ buckets,
    int        cap,
    int*       __restrict__ ovf_cnt,
    int*       __restrict__ ovf)
{
    int e = blockIdx.x * blockDim.x + threadIdx.x;
    if (e >= NUM_EDGES) return;
    int t = tgt[e];
    int idx = atomicAdd(&cursor[t], 1);
    if (idx < cap) {
        buckets[(size_t)t * cap + idx] = e;
    } else {
        int o = atomicAdd(ovf_cnt, 1);
        if (o < OVF_CAP) { ovf[2 * o] = e; ovf[2 * o + 1] = t; }
    }
}

// Phase 2: one 64-lane wave per node; lane owns one float4 of the 256-float row.
// Bucket list is preloaded lane-parallel and broadcast via __shfl (no per-iter
// pointer chase); msg rows stream as coalesced 1KB bursts, 4-deep load ILP.
// Writes EVERY row (deg=0 -> zeros), so d_out needs no pre-zeroing.
__global__ __launch_bounds__(256) void gather_sum(
    const float4* __restrict__ msg4,
    const int*    __restrict__ cursor,
    const int*    __restrict__ buckets,
    float4*       __restrict__ out4,
    int           cap)
{
    int g    = threadIdx.x >> 6;          // 4 node-waves per block
    int lane = threadIdx.x & 63;
    int n    = blockIdx.x * 4 + g;
    if (n >= NUM_NODES) return;

    int deg = cursor[n];
    if (deg > cap) deg = cap;
    const int* bl = buckets + (size_t)n * cap;

    float4 acc = make_float4(0.f, 0.f, 0.f, 0.f);

    // batch 1: first up to 64 edges, preloaded one-per-lane
    int m1  = deg < 64 ? deg : 64;
    int e_l = (lane < m1) ? bl[lane] : 0;
    int i = 0;
    for (; i + 4 <= m1; i += 4) {
        int e0 = __shfl(e_l, i),     e1 = __shfl(e_l, i + 1);
        int e2 = __shfl(e_l, i + 2), e3 = __shfl(e_l, i + 3);
        float4 v0 = msg4[(size_t)e0 * 64 + lane];
        float4 v1 = msg4[(size_t)e1 * 64 + lane];
        float4 v2 = msg4[(size_t)e2 * 64 + lane];
        float4 v3 = msg4[(size_t)e3 * 64 + lane];
        acc.x += (v0.x + v1.x) + (v2.x + v3.x);
        acc.y += (v0.y + v1.y) + (v2.y + v3.y);
        acc.z += (v0.z + v1.z) + (v2.z + v3.z);
        acc.w += (v0.w + v1.w) + (v2.w + v3.w);
    }
    for (; i < m1; ++i) {
        int e = __shfl(e_l, i);
        float4 v = msg4[(size_t)e * 64 + lane];
        acc.x += v.x; acc.y += v.y; acc.z += v.z; acc.w += v.w;
    }

    // batch 2: edges 64..deg (rare: P(deg>64) ~ 4e-6 per node)
    if (deg > 64) {
        int m2   = deg - 64;
        int e_l2 = (lane < m2) ? bl[64 + lane] : 0;
        for (int j = 0; j < m2; ++j) {
            int e = __shfl(e_l2, j);
            float4 v = msg4[(size_t)e * 64 + lane];
            acc.x += v.x; acc.y += v.y; acc.z += v.z; acc.w += v.w;
        }
    }

    out4[(size_t)n * 64 + lane] = acc;
}

// Phase 3: atomically add overflow edges (expected count: 0 -> ~instant no-op).
__global__ __launch_bounds__(256) void ovf_cleanup(
    const float* __restrict__ msg,
    float*       __restrict__ out,
    const int*   __restrict__ ovf_cnt,
    const int*   __restrict__ ovf)
{
    int cnt = *ovf_cnt;
    if (cnt > OVF_CAP) cnt = OVF_CAP;
    for (int o = blockIdx.x; o < cnt; o += gridDim.x) {
        int e = ovf[2 * o], t = ovf[2 * o + 1];
        const float* m  = msg + (size_t)e * FEAT_DIM;
        float*       op = out + (size_t)t * FEAT_DIM;
        for (int f = threadIdx.x; f < FEAT_DIM; f += blockDim.x)
            atomicAdd(op + f, m[f]);
    }
}

// Correct-but-slow fallback if ws is unexpectedly small (round-0 kernel).
__global__ __launch_bounds__(256) void scatter_add_kernel(
    const float4* __restrict__ msg4,
    const int*    __restrict__ tgt,
    float*        __restrict__ out)
{
    int idx = blockIdx.x * blockDim.x + threadIdx.x;
    int e  = idx >> 6;
    int f4 = idx & 63;
    if (e >= NUM_EDGES) return;
    float4 v = msg4[(size_t)e * 64 + f4];
    int t = tgt[e];
    float* o = out + (size_t)t * FEAT_DIM + f4 * 4;
    atomicAdd(o + 0, v.x);
    atomicAdd(o + 1, v.y);
    atomicAdd(o + 2, v.z);
    atomicAdd(o + 3, v.w);
}

extern "C" void kernel_launch(void* const* d_in, const int* in_sizes, int n_in,
                              void* d_out, int out_size, void* d_ws, size_t ws_size,
                              hipStream_t stream) {
    const float*  msg  = (const float*)d_in[0];
    const float4* msg4 = (const float4*)d_in[0];
    const int*    eidx = (const int*)d_in[1];   // [2, NUM_EDGES] row-major int32
    const int*    tgt  = eidx + NUM_EDGES;      // edge_index[1]
    float*        out  = (float*)d_out;

    const size_t header = ((size_t)NUM_NODES + 1 + 2 * OVF_CAP) * sizeof(int);

    // Pick bucket capacity from available workspace: prefer 128, accept >=64.
    int cap = 0;
    if (ws_size > header) {
        size_t avail = (ws_size - header) / ((size_t)NUM_NODES * sizeof(int));
        cap = avail >= 128 ? 128 : (avail >= 64 ? 64 : 0);
    }

    if (cap > 0) {
        int* cursor  = (int*)d_ws;
        int* ovf_cnt = cursor + NUM_NODES;
        int* ovf     = ovf_cnt + 1;
        int* buckets = ovf + 2 * OVF_CAP;

        // zero cursor + ovf_cnt in one memset (ovf entries don't need zeroing)
        hipMemsetAsync(cursor, 0, ((size_t)NUM_NODES + 1) * sizeof(int), stream);

        fill_buckets<<<(NUM_EDGES + 255) / 256, 256, 0, stream>>>(
            tgt, cursor, buckets, cap, ovf_cnt, ovf);
        gather_sum<<<NUM_NODES / 4, 256, 0, stream>>>(
            msg4, cursor, buckets, (float4*)out, cap);
        ovf_cleanup<<<8, 256, 0, stream>>>(msg, out, ovf_cnt, ovf);
    } else {
        hipMemsetAsync(out, 0, (size_t)out_size * sizeof(float), stream);
        const int total = NUM_EDGES * 64;
        scatter_add_kernel<<<(total + 255) / 256, 256, 0, stream>>>(msg4, tgt, out);
    }
}

// Round 5
// 95.757 us; speedup vs baseline: 11.1730x; 1.0025x over previous
//
#include <hip/hip_runtime.h>

#define NUM_NODES 10000
#define NUM_EDGES 320000
#define FEAT_DIM  256
#define OVF_CAP   4096   // overflow edge slots (paranoia; expected 0 used)

typedef float  f32x4 __attribute__((ext_vector_type(4)));  // native vec for nt builtins

// ws layout:
//   int cursor[NUM_NODES]       -- per-node degree counters
//   int ovf_cnt                 -- overflow counter
//   int ovf[2*OVF_CAP]          -- (edge, node) overflow pairs
//   int buckets[NUM_NODES*cap]  -- per-node edge-id lists (cap chosen at runtime)

// Phase 1: bucket edge ids per target node. 4 edges/thread, vectorized tgt read.
__global__ __launch_bounds__(256) void fill_buckets(
    const int* __restrict__ tgt,
    int*       __restrict__ cursor,
    int*       __restrict__ buckets,
    int        cap,
    int*       __restrict__ ovf_cnt,
    int*       __restrict__ ovf)
{
    int base = (blockIdx.x * blockDim.x + threadIdx.x) * 4;
    if (base >= NUM_EDGES) return;                    // NUM_EDGES % 4 == 0
    int4 t4 = *(const int4*)(tgt + base);
    int ts[4] = {t4.x, t4.y, t4.z, t4.w};
    #pragma unroll
    for (int k = 0; k < 4; ++k) {
        int e = base + k;
        int t = ts[k];
        int idx = atomicAdd(&cursor[t], 1);
        if (idx < cap) {
            buckets[(size_t)t * cap + idx] = e;
        } else {
            int o = atomicAdd(ovf_cnt, 1);
            if (o < OVF_CAP) { ovf[2 * o] = e; ovf[2 * o + 1] = t; }
        }
    }
}

__device__ __forceinline__ f32x4 nt_load4(const f32x4* p) {
    return __builtin_nontemporal_load(p);
}

// Phase 2: one 64-lane wave per node; lane owns one float4 of the 256-float row.
// Bucket list preloaded lane-parallel, broadcast via __shfl; msg rows stream as
// nontemporal coalesced 1KB bursts with 8-deep load ILP. Writes EVERY row
// (deg=0 -> zeros), so d_out needs no pre-zeroing.
__global__ __launch_bounds__(256) void gather_sum(
    const f32x4* __restrict__ msg4,
    const int*   __restrict__ cursor,
    const int*   __restrict__ buckets,
    f32x4*       __restrict__ out4,
    int          cap)
{
    int g    = threadIdx.x >> 6;          // 4 node-waves per block
    int lane = threadIdx.x & 63;
    int n    = blockIdx.x * 4 + g;
    if (n >= NUM_NODES) return;

    int deg = cursor[n];
    if (deg > cap) deg = cap;
    const int* bl = buckets + (size_t)n * cap;

    f32x4 acc = (f32x4)(0.f);

    // batch 1: first up to 64 edges, preloaded one-per-lane
    int m1  = deg < 64 ? deg : 64;
    int e_l = (lane < m1) ? bl[lane] : 0;
    int i = 0;
    for (; i + 8 <= m1; i += 8) {
        int e0 = __shfl(e_l, i),     e1 = __shfl(e_l, i + 1);
        int e2 = __shfl(e_l, i + 2), e3 = __shfl(e_l, i + 3);
        int e4 = __shfl(e_l, i + 4), e5 = __shfl(e_l, i + 5);
        int e6 = __shfl(e_l, i + 6), e7 = __shfl(e_l, i + 7);
        f32x4 v0 = nt_load4(msg4 + (size_t)e0 * 64 + lane);
        f32x4 v1 = nt_load4(msg4 + (size_t)e1 * 64 + lane);
        f32x4 v2 = nt_load4(msg4 + (size_t)e2 * 64 + lane);
        f32x4 v3 = nt_load4(msg4 + (size_t)e3 * 64 + lane);
        f32x4 v4 = nt_load4(msg4 + (size_t)e4 * 64 + lane);
        f32x4 v5 = nt_load4(msg4 + (size_t)e5 * 64 + lane);
        f32x4 v6 = nt_load4(msg4 + (size_t)e6 * 64 + lane);
        f32x4 v7 = nt_load4(msg4 + (size_t)e7 * 64 + lane);
        acc += ((v0 + v1) + (v2 + v3)) + ((v4 + v5) + (v6 + v7));
    }
    for (; i + 4 <= m1; i += 4) {
        int e0 = __shfl(e_l, i),     e1 = __shfl(e_l, i + 1);
        int e2 = __shfl(e_l, i + 2), e3 = __shfl(e_l, i + 3);
        f32x4 v0 = nt_load4(msg4 + (size_t)e0 * 64 + lane);
        f32x4 v1 = nt_load4(msg4 + (size_t)e1 * 64 + lane);
        f32x4 v2 = nt_load4(msg4 + (size_t)e2 * 64 + lane);
        f32x4 v3 = nt_load4(msg4 + (size_t)e3 * 64 + lane);
        acc += (v0 + v1) + (v2 + v3);
    }
    for (; i < m1; ++i) {
        int e = __shfl(e_l, i);
        acc += nt_load4(msg4 + (size_t)e * 64 + lane);
    }

    // batch 2: edges 64..deg (P(deg>64) ~ 4e-6 per node; correctness only)
    if (deg > 64) {
        int m2   = deg - 64;
        int e_l2 = (lane < m2) ? bl[64 + lane] : 0;
        for (int j = 0; j < m2; ++j) {
            int e = __shfl(e_l2, j);
            acc += nt_load4(msg4 + (size_t)e * 64 + lane);
        }
    }

    __builtin_nontemporal_store(acc, out4 + (size_t)n * 64 + lane);
}

// Phase 3: atomically add overflow edges (expected count: 0 -> ~instant no-op).
__global__ __launch_bounds__(256) void ovf_cleanup(
    const float* __restrict__ msg,
    float*       __restrict__ out,
    const int*   __restrict__ ovf_cnt,
    const int*   __restrict__ ovf)
{
    int cnt = *ovf_cnt;
    if (cnt > OVF_CAP) cnt = OVF_CAP;
    for (int o = blockIdx.x; o < cnt; o += gridDim.x) {
        int e = ovf[2 * o], t = ovf[2 * o + 1];
        const float* m  = msg + (size_t)e * FEAT_DIM;
        float*       op = out + (size_t)t * FEAT_DIM;
        for (int f = threadIdx.x; f < FEAT_DIM; f += blockDim.x)
            atomicAdd(op + f, m[f]);
    }
}

// Correct-but-slow fallback if ws is unexpectedly small (round-0 kernel).
__global__ __launch_bounds__(256) void scatter_add_kernel(
    const float4* __restrict__ msg4,
    const int*    __restrict__ tgt,
    float*        __restrict__ out)
{
    int idx = blockIdx.x * blockDim.x + threadIdx.x;
    int e  = idx >> 6;
    int f4 = idx & 63;
    if (e >= NUM_EDGES) return;
    float4 v = msg4[(size_t)e * 64 + f4];
    int t = tgt[e];
    float* o = out + (size_t)t * FEAT_DIM + f4 * 4;
    atomicAdd(o + 0, v.x);
    atomicAdd(o + 1, v.y);
    atomicAdd(o + 2, v.z);
    atomicAdd(o + 3, v.w);
}

extern "C" void kernel_launch(void* const* d_in, const int* in_sizes, int n_in,
                              void* d_out, int out_size, void* d_ws, size_t ws_size,
                              hipStream_t stream) {
    const float*  msg   = (const float*)d_in[0];
    const f32x4*  msg4  = (const f32x4*)d_in[0];
    const int*    eidx  = (const int*)d_in[1];   // [2, NUM_EDGES] row-major int32
    const int*    tgt   = eidx + NUM_EDGES;      // edge_index[1]
    float*        out   = (float*)d_out;

    const size_t header = ((size_t)NUM_NODES + 1 + 2 * OVF_CAP) * sizeof(int);

    // Pick bucket capacity from available workspace: prefer 128, accept >=64.
    int cap = 0;
    if (ws_size > header) {
        size_t avail = (ws_size - header) / ((size_t)NUM_NODES * sizeof(int));
        cap = avail >= 128 ? 128 : (avail >= 64 ? 64 : 0);
    }

    if (cap > 0) {
        int* cursor  = (int*)d_ws;
        int* ovf_cnt = cursor + NUM_NODES;
        int* ovf     = ovf_cnt + 1;
        int* buckets = ovf + 2 * OVF_CAP;

        // zero cursor + ovf_cnt in one memset (ovf entries don't need zeroing)
        (void)hipMemsetAsync(cursor, 0, ((size_t)NUM_NODES + 1) * sizeof(int), stream);

        fill_buckets<<<(NUM_EDGES / 4 + 255) / 256, 256, 0, stream>>>(
            tgt, cursor, buckets, cap, ovf_cnt, ovf);
        gather_sum<<<NUM_NODES / 4, 256, 0, stream>>>(
            msg4, cursor, buckets, (f32x4*)out, cap);
        ovf_cleanup<<<8, 256, 0, stream>>>(msg, out, ovf_cnt, ovf);
    } else {
        (void)hipMemsetAsync(out, 0, (size_t)out_size * sizeof(float), stream);
        const int total = NUM_EDGES * 64;
        scatter_add_kernel<<<(total + 255) / 256, 256, 0, stream>>>((const float4*)d_in[0], tgt, out);
    }
}